// Round 2
// baseline (319.266 us; speedup 1.0000x reference)
//
#include <hip/hip_runtime.h>
#include <hip/hip_bf16.h>

#define NHEAD 4
#define FIN   768
#define FOUT  64
#define BSZ   4
#define NSEQ  2048
#define BH    (BSZ*NHEAD)
#define LOG2E 1.44269504088896f

typedef __attribute__((ext_vector_type(8)))  short bf16x8;   // MFMA A/B frag
typedef __attribute__((ext_vector_type(16))) float f32x16;   // MFMA 32x32 C/D
typedef __attribute__((ext_vector_type(8)))  unsigned short u16x8;
typedef __attribute__((ext_vector_type(4)))  unsigned short u16x4;
typedef __attribute__((ext_vector_type(4)))  unsigned u32x4;

__device__ __forceinline__ unsigned short f2bf(float f){
  unsigned b = __float_as_uint(f);
  return (unsigned short)((b + 0x7fffu + ((b >> 16) & 1u)) >> 16);
}
__device__ __forceinline__ float fexp2(float x){
#if __has_builtin(__builtin_amdgcn_exp2f)
  return __builtin_amdgcn_exp2f(x);
#else
  return exp2f(x);
#endif
}
__device__ __forceinline__ unsigned pkbf(float lo, float hi){
#if __has_builtin(__builtin_amdgcn_cvt_pk_bf16_f32)
  typedef __attribute__((ext_vector_type(2))) __bf16 bf2;
  union { bf2 v; unsigned u; } cv;
  cv.v = __builtin_amdgcn_cvt_pk_bf16_f32(lo, hi);
  return cv.u;
#else
  return (unsigned)f2bf(lo) | ((unsigned)f2bf(hi) << 16);
#endif
}
// fast tanh via exp2: tanh(v) = 1 - 2/(exp2(2*log2e*v)+1). |err| ~1e-7.
__device__ __forceinline__ float fast_tanh(float v){
  const float e = fexp2(v * (2.0f*LOG2E));
#if __has_builtin(__builtin_amdgcn_rcpf)
  return 1.0f - 2.0f*__builtin_amdgcn_rcpf(e + 1.0f);
#else
  return 1.0f - 2.0f/(e + 1.0f);
#endif
}
// async global->LDS, 16B per lane. LDS dest is wave-uniform base + lane*16.
__device__ __forceinline__ void gll16(const void* g, void* l){
  __builtin_amdgcn_global_load_lds(
      (const __attribute__((address_space(1))) unsigned*)g,
      (__attribute__((address_space(3))) unsigned*)l, 16, 0, 0);
}

// Device-scope grid barrier. Correct ONLY when all blocks co-resident:
// grid=512, __launch_bounds__(512,4) -> 2 blocks/CU x 256 CU. Counter must be
// zeroed by host (hipMemsetAsync) before launch.
__device__ __forceinline__ void gbar(unsigned* c, unsigned target){
  __syncthreads();                      // drains all block stores (vmcnt 0)
  if (threadIdx.x == 0){
    __threadfence();                    // release: L2 writeback, device scope
    __hip_atomic_fetch_add(c, 1u, __ATOMIC_RELAXED, __HIP_MEMORY_SCOPE_AGENT);
    int guard = 0;
    while (__hip_atomic_load(c, __ATOMIC_RELAXED, __HIP_MEMORY_SCOPE_AGENT) < target
           && ++guard < (1 << 24))
      __builtin_amdgcn_s_sleep(2);
  }
  __syncthreads();
  __threadfence();                      // acquire: invalidate stale L1/L2
}

// ---------------------------------------------------------------------------
// Fused kernel: phase0 (fp32->bf16 pre-swizzled images) -> grid barrier ->
// phase1 (h' GEMM + attn_src/dst partials) -> grid barrier -> phase2 (softmax
// + P@H'). Phase bodies identical to the round-1 three-kernel version.
//
// Image spec:  16B unit (row, it, p): p in [0,16), half hf=p>>3, chunk cs=p&7
//   holds k = it*128 + hf*64 + ((cs ^ (row&7))*8 + j, j=0..7, as bf16.
// h_bf: [row 8192][it 6][p 16] units (12.58 MB); w_bf: [head 4][it 6][o 64][p 16]
// ---------------------------------------------------------------------------
__global__ __launch_bounds__(512, 4) void k_fused(
    const float* __restrict__ h, const float* __restrict__ w,
    const float* __restrict__ a_src, const float* __restrict__ a_dst,
    const float* __restrict__ bias, float* __restrict__ out,
    unsigned short* __restrict__ hpz2, float* __restrict__ srcv,
    float* __restrict__ dstv, unsigned short* __restrict__ h_bf,
    unsigned short* __restrict__ w_bf, unsigned* __restrict__ bar)
{
  __shared__ __align__(16) char smem[65536];
  const int tid = threadIdx.x;
  const int bid = blockIdx.x;
  const int wave = tid >> 6, lane = tid & 63;
  const int l32 = lane & 31, h32 = lane >> 5;

  // ---------------- Phase 0: convert h and w into pre-swizzled bf16 ----------
  {
    #pragma unroll
    for (int c = 0; c < 3; ++c){                     // 3*262144 = 786432 h-units
      const int gid = c*262144 + bid*512 + tid;
      const int row = gid / 96;
      const int rem = gid - row*96;
      const int it  = rem >> 4, p = rem & 15;
      const float* src = h + (size_t)row*FIN + it*128 + ((p>>3)<<6)
                           + (((p & 7) ^ (row & 7)) << 3);
      const float4 a = *(const float4*)src;
      const float4 b = *(const float4*)(src + 4);
      u32x4 pk;
      pk[0] = pkbf(a.x, a.y); pk[1] = pkbf(a.z, a.w);
      pk[2] = pkbf(b.x, b.y); pk[3] = pkbf(b.z, b.w);
      *(u32x4*)((char*)h_bf + (size_t)gid*16) = pk;  // perfectly coalesced
    }
    if (bid < 48){                                   // 48*512 = 24576 w-units
      const int wid = bid*512 + tid;
      const int p   = wid & 15, o = (wid >> 4) & 63, hi6 = wid >> 10;
      const int hd  = hi6 / 6, it = hi6 - hd*6;
      const int k0 = it*128 + ((p>>3)<<6) + (((p & 7) ^ (o & 7)) << 3);
      const float* sw = w + (size_t)hd*FIN*FOUT + (size_t)k0*FOUT + o;
      float r0 = sw[0*FOUT], r1 = sw[1*FOUT], r2 = sw[2*FOUT], r3 = sw[3*FOUT];
      float r4 = sw[4*FOUT], r5 = sw[5*FOUT], r6 = sw[6*FOUT], r7 = sw[7*FOUT];
      u32x4 pk;
      pk[0] = pkbf(r0, r1); pk[1] = pkbf(r2, r3);
      pk[2] = pkbf(r4, r5); pk[3] = pkbf(r6, r7);
      *(u32x4*)((char*)w_bf + (size_t)wid*16) = pk;
    }
  }
  gbar(bar + 0, 512);

  // ---------------- Phase 1: h' = h @ w_head, srcv/dstv partials -------------
  {
    float* psumS = (float*)(smem + 16384);
    float* psumD = (float*)(smem + 16896);
    char*  Tt    = smem + 32768;

    const int bh1  = (bid & 7) | (((bid >> 3) & 1) << 3);
    const int head = bh1 & 3;
    const int jbase = (bid >> 4) << 6;
    const int i0a   = (bh1 >> 2)*NSEQ + jbase;
    const int wm = wave & 1, wn = (wave >> 1) & 1, kw = wave >> 2;

    f32x16 acc = {0,0,0,0,0,0,0,0,0,0,0,0,0,0,0,0};

    const int rowL = wave*4 + (lane >> 4);
    const int p16  = lane & 15;
    const char* sA = (const char*)h_bf + ((size_t)(i0a + rowL)*96 + p16)*16;
    const char* sB = (const char*)w_bf + (size_t)(head*6)*16384 + rowL*256 + p16*16;

    {
      char* AbW = smem +         wave*1024;
      char* BbW = smem + 32768 + wave*1024;
      gll16(sA,         AbW);
      gll16(sA + 49152, AbW + 8192);
      gll16(sB,         BbW);
      gll16(sB + 8192,  BbW + 8192);
    }
    __syncthreads();

    for (int it = 0; it < 6; ++it){
      const int bb = it & 1;
      char* Ab = smem +         bb*16384;
      char* Bb = smem + 32768 + bb*16384;
      if (it < 5){
        char* AbW = smem +         (bb^1)*16384 + wave*1024;
        char* BbW = smem + 32768 + (bb^1)*16384 + wave*1024;
        const char* sAi = sA + (size_t)(it+1)*256;
        const char* sBi = sB + (size_t)(it+1)*16384;
        gll16(sAi,         AbW);
        gll16(sAi + 49152, AbW + 8192);
        gll16(sBi,         BbW);
        gll16(sBi + 8192,  BbW + 8192);
      }
      #pragma unroll
      for (int s = 0; s < 4; ++s){
        const int slot = (((s*2 + h32) ^ (l32 & 7)) << 4);
        bf16x8 av = *(const bf16x8*)(Ab + (wm*32 + l32)*256 + kw*128 + slot);
        bf16x8 bv = *(const bf16x8*)(Bb + (wn*32 + l32)*256 + kw*128 + slot);
        acc = __builtin_amdgcn_mfma_f32_32x32x16_bf16(av, bv, acc, 0, 0, 0);
      }
      __syncthreads();
    }

    if (kw == 1) *(f32x16*)(smem + (size_t)((wave & 3)*64 + lane)*64) = acc;
    __syncthreads();
    if (kw == 0){
      acc += *(const f32x16*)(smem + (size_t)((wave & 3)*64 + lane)*64);
      const float as = a_src[head*64 + wn*32 + l32];
      const float ad = a_dst[head*64 + wn*32 + l32];
      #pragma unroll
      for (int rb2 = 0; rb2 < 4; ++rb2){
        const int jb = wm*32 + rb2*8 + h32*4;
        u16x4 c4;
        #pragma unroll
        for (int q = 0; q < 4; ++q){
          const float v = acc[rb2*4 + q];
          c4[q] = f2bf(v);
          const float t = fast_tanh(v);
          float ps = t*as, pd = t*ad;
          ps += __shfl_xor(ps, 1);  ps += __shfl_xor(ps, 2);  ps += __shfl_xor(ps, 4);
          ps += __shfl_xor(ps, 8);  ps += __shfl_xor(ps, 16);
          pd += __shfl_xor(pd, 1);  pd += __shfl_xor(pd, 2);  pd += __shfl_xor(pd, 4);
          pd += __shfl_xor(pd, 8);  pd += __shfl_xor(pd, 16);
          if (l32 == 0){
            psumS[(jb + q)*2 + wn] = ps;
            psumD[(jb + q)*2 + wn] = pd;
          }
        }
        const int orow = wn*32 + l32;
        const int slot = ((jb >> 3) & 7) ^ (orow & 7);
        *(u16x4*)(Tt + orow*128 + slot*16 + (jb & 7)*2) = c4;
      }
    }
    __syncthreads();

    {
      const int o = tid & 63, c = tid >> 6;
      u16x8 val = *(const u16x8*)(Tt + o*128 + ((c ^ (o & 7)) << 4));
      *(u16x8*)((char*)hpz2 + ((size_t)(bh1*256 + (jbase >> 3) + c)*64 + o)*16) = val;
    }
    if (tid < 64){
      srcv[(size_t)bh1*NSEQ + jbase + tid] = (psumS[tid*2] + psumS[tid*2 + 1]) * LOG2E;
      dstv[(size_t)bh1*NSEQ + jbase + tid] = (psumD[tid*2] + psumD[tid*2 + 1]) * LOG2E;
    }
  }
  gbar(bar + 1, 512);

  // ---------------- Phase 2: p = exp2(lrelu(s+d)), out = (P@H')/l + bias -----
  {
    float* Lbuf = (float*)(smem + 32768);

    const int bh  = (bid & 7) | (((bid >> 3) & 1) << 3);
    const int i0  = (bid >> 4) << 6;
    const int wm = wave & 1, jw = wave >> 1;

    const float s2 = srcv[(size_t)bh*NSEQ + i0 + wm*32 + l32];
    const float u_ = s2;
    const float v_ = 0.2f*s2;
    const float* dptr = dstv + (size_t)bh*NSEQ;

    const u16x8* gp = (const u16x8*)((const char*)hpz2 + (size_t)bh*256*64*16);

    f32x16 accO0 = {0,0,0,0,0,0,0,0,0,0,0,0,0,0,0,0};
    f32x16 accO1 = {0,0,0,0,0,0,0,0,0,0,0,0,0,0,0,0};
    float lpart = 0.f;

    *(u16x8*)(smem + tid*16)         = gp[tid];
    *(u16x8*)(smem + (tid + 512)*16) = gp[tid + 512];
    __syncthreads();

    for (int wt = 0; wt < 16; ++wt){
      char* cur = smem + (wt & 1)*16384;
      char* nxt = smem + ((wt + 1) & 1)*16384;
      u16x8 r0, r1;
      if (wt < 15){
        r0 = gp[(wt+1)*1024 + tid];
        r1 = gp[(wt+1)*1024 + tid + 512];
      }
      #pragma unroll
      for (int stl = 0; stl < 2; ++stl){
        const int Jl = jw*4 + stl*2 + h32;
        const int j0 = (wt*16 + Jl)*8;
        float4 d0 = *(const float4*)(dptr + j0);
        float4 d1 = *(const float4*)(dptr + j0 + 4);
        float e0,e1,e2,e3,e4,e5,e6,e7;
        e0 = fexp2(fmaxf(u_ + d0.x, fmaf(0.2f, d0.x, v_)));
        e1 = fexp2(fmaxf(u_ + d0.y, fmaf(0.2f, d0.y, v_)));
        e2 = fexp2(fmaxf(u_ + d0.z, fmaf(0.2f, d0.z, v_)));
        e3 = fexp2(fmaxf(u_ + d0.w, fmaf(0.2f, d0.w, v_)));
        e4 = fexp2(fmaxf(u_ + d1.x, fmaf(0.2f, d1.x, v_)));
        e5 = fexp2(fmaxf(u_ + d1.y, fmaf(0.2f, d1.y, v_)));
        e6 = fexp2(fmaxf(u_ + d1.z, fmaf(0.2f, d1.z, v_)));
        e7 = fexp2(fmaxf(u_ + d1.w, fmaf(0.2f, d1.w, v_)));
        lpart += ((e0+e1)+(e2+e3)) + ((e4+e5)+(e6+e7));
        u32x4 pk;
        pk[0] = pkbf(e0, e1); pk[1] = pkbf(e2, e3);
        pk[2] = pkbf(e4, e5); pk[3] = pkbf(e6, e7);
        const bf16x8 pA = __builtin_bit_cast(bf16x8, pk);
        const bf16x8 bv0 = *(const bf16x8*)(cur + (Jl*64 +      l32)*16);
        const bf16x8 bv1 = *(const bf16x8*)(cur + (Jl*64 + 32 + l32)*16);
        accO0 = __builtin_amdgcn_mfma_f32_32x32x16_bf16(pA, bv0, accO0, 0, 0, 0);
        accO1 = __builtin_amdgcn_mfma_f32_32x32x16_bf16(pA, bv1, accO1, 0, 0, 0);
      }
      if (wt < 15){
        *(u16x8*)(nxt + tid*16)         = r0;
        *(u16x8*)(nxt + (tid + 512)*16) = r1;
      }
      __syncthreads();
    }

    lpart += __shfl_xor(lpart, 32);
    if (lane < 32) Lbuf[(wm*4 + jw)*32 + l32] = lpart;

    const float4 bia = *(const float4*)(bias + (tid & 15)*4);
    #pragma unroll
    for (int ph = 0; ph < 2; ++ph){
      __syncthreads();
      if (wm == ph){
        float* ob = (float*)smem;
        #pragma unroll
        for (int reg = 0; reg < 16; ++reg){
          const int m = (reg & 3) + 8*(reg >> 2) + 4*h32;
          ob[(jw*32 + m)*64 +      l32] = accO0[reg];
          ob[(jw*32 + m)*64 + 32 + l32] = accO1[reg];
        }
      }
      __syncthreads();
      {
        const int i = tid >> 4, o4 = (tid & 15)*4;
        const float* ob = (const float*)smem;
        float4 v0 = *(const float4*)(ob + (0*32 + i)*64 + o4);
        float4 v1 = *(const float4*)(ob + (1*32 + i)*64 + o4);
        float4 v2 = *(const float4*)(ob + (2*32 + i)*64 + o4);
        float4 v3 = *(const float4*)(ob + (3*32 + i)*64 + o4);
        const float l = Lbuf[(ph*4+0)*32 + i] + Lbuf[(ph*4+1)*32 + i]
                      + Lbuf[(ph*4+2)*32 + i] + Lbuf[(ph*4+3)*32 + i];
        const float r = 1.f / l;
        float4 res;
        res.x = (v0.x + v1.x + v2.x + v3.x)*r + bia.x;
        res.y = (v0.y + v1.y + v2.y + v3.y)*r + bia.y;
        res.z = (v0.z + v1.z + v2.z + v3.z)*r + bia.z;
        res.w = (v0.w + v1.w + v2.w + v3.w)*r + bia.w;
        *(float4*)(out + ((size_t)bh*NSEQ + i0 + ph*32 + i)*64 + o4) = res;
      }
    }
  }
}

// ---------------------------------------------------------------------------
extern "C" void kernel_launch(void* const* d_in, const int* in_sizes, int n_in,
                              void* d_out, int out_size, void* d_ws, size_t ws_size,
                              hipStream_t stream)
{
  const float* h     = (const float*)d_in[0];
  const float* w     = (const float*)d_in[1];
  const float* a_src = (const float*)d_in[2];
  const float* a_dst = (const float*)d_in[3];
  const float* bias  = (const float*)d_in[4];
  float* out = (float*)d_out;

  char* ws = (char*)d_ws;
  unsigned short* hpz2 = (unsigned short*)ws;                 // 4 MB bf16 chunk-linear
  float* srcv = (float*)(ws + (4u<<20));                      // 128 KB (log2-scaled)
  float* dstv = (float*)(ws + (4u<<20) + (128u<<10));         // 128 KB (log2-scaled)
  unsigned short* h_bf = (unsigned short*)(ws + (8u<<20));    // 12.58 MB pre-swizzled
  unsigned short* w_bf = (unsigned short*)(ws + (8u<<20) + 12582912u); // 384 KB
  unsigned* bar = (unsigned*)(ws + (24u<<20));                // 2 barrier counters

  hipMemsetAsync(bar, 0, 256, stream);
  k_fused<<<512, 512, 0, stream>>>(h, w, a_src, a_dst, bias, out,
                                   hpz2, srcv, dstv, h_bf, w_bf, bar);
}

// Round 3
// 115.707 us; speedup vs baseline: 2.7593x; 2.7593x over previous
//
#include <hip/hip_runtime.h>
#include <hip/hip_bf16.h>

#define NHEAD 4
#define FIN   768
#define FOUT  64
#define BSZ   4
#define NSEQ  2048
#define BH    (BSZ*NHEAD)
#define LOG2E 1.44269504088896f

typedef __attribute__((ext_vector_type(8)))  short bf16x8;   // MFMA A/B frag
typedef __attribute__((ext_vector_type(16))) float f32x16;   // MFMA 32x32 C/D
typedef __attribute__((ext_vector_type(8)))  unsigned short u16x8;
typedef __attribute__((ext_vector_type(4)))  unsigned short u16x4;
typedef __attribute__((ext_vector_type(4)))  unsigned u32x4;

__device__ __forceinline__ unsigned short f2bf(float f){
  unsigned b = __float_as_uint(f);
  return (unsigned short)((b + 0x7fffu + ((b >> 16) & 1u)) >> 16);
}
__device__ __forceinline__ float fexp2(float x){
#if __has_builtin(__builtin_amdgcn_exp2f)
  return __builtin_amdgcn_exp2f(x);
#else
  return exp2f(x);
#endif
}
__device__ __forceinline__ unsigned pkbf(float lo, float hi){
#if __has_builtin(__builtin_amdgcn_cvt_pk_bf16_f32)
  typedef __attribute__((ext_vector_type(2))) __bf16 bf2;
  union { bf2 v; unsigned u; } cv;
  cv.v = __builtin_amdgcn_cvt_pk_bf16_f32(lo, hi);
  return cv.u;
#else
  return (unsigned)f2bf(lo) | ((unsigned)f2bf(hi) << 16);
#endif
}

// ---------------------------------------------------------------------------
// Kernel A (round-0 proven version, 119.06 us config): h' = h @ w_head via
// 32x32x16 MFMA, A and B staged from fp32 with inline convert, double-
// buffered, one barrier per K-iter. XCD swizzle keeps one head's w per XCD.
// ---------------------------------------------------------------------------
__global__ __launch_bounds__(512, 2) void k_hprime(
    const float* __restrict__ h, const float* __restrict__ w,
    const float* __restrict__ a_src, const float* __restrict__ a_dst,
    unsigned short* __restrict__ hpz2, float* __restrict__ srcv,
    float* __restrict__ dstv)
{
  __shared__ __align__(16) char smem[65536];
  // A0@0, A1@16384, B0@32768, B1@49152
  // epilogue overlays: scratch@0 (16K), psumS@16384, psumD@16896, Tt@32768 (8K)
  float* psumS = (float*)(smem + 16384);
  float* psumD = (float*)(smem + 16896);
  char*  Tt    = smem + 32768;

  const int tid  = threadIdx.x;
  const int bid  = blockIdx.x;
  const int bh1  = (bid & 7) | (((bid >> 3) & 1) << 3);
  const int head = bh1 & 3;
  const int jbase = (bid >> 4) << 6;                 // within-sequence row base
  const int i0a   = (bh1 >> 2)*NSEQ + jbase;         // global flat row
  const int wave = tid >> 6, lane = tid & 63;
  const int wm = wave & 1, wn = (wave >> 1) & 1, kw = wave >> 2;
  const int l32 = lane & 31, h32 = lane >> 5;

  f32x16 acc = {0,0,0,0,0,0,0,0,0,0,0,0,0,0,0,0};

  // A staging map: row sr, chunk sc (r9-proven)
  const int sr = tid >> 3, sc = tid & 7;
  const float* hA = h + (size_t)(i0a + sr)*FIN + sc*8;
  const int aslot = (sc ^ (sr & 7)) << 4;

  // B staging map: o = lane (coalesced), halves g0 = cc, g1 = cc+8
  const int ob = tid & 63, cc = tid >> 6;
  const float* wsrc = w + (size_t)head*FIN*FOUT + ob;   // + f*64
  const int bslot0 = ((cc & 7) ^ (ob & 7)) << 4;        // half 0 slot

  // prologue: prefetch iter 0
  float4 ra0 = *(const float4*)(hA);
  float4 ra1 = *(const float4*)(hA + 4);
  float4 ra2 = *(const float4*)(hA + 64);
  float4 ra3 = *(const float4*)(hA + 68);
  float rb[16];
  #pragma unroll
  for (int j = 0; j < 8; ++j){
    rb[j]     = wsrc[(size_t)(cc*8 + j)*FOUT];          // g0 = cc   (k 0..63)
    rb[8 + j] = wsrc[(size_t)(64 + cc*8 + j)*FOUT];     // g1 = cc+8 (k 64..127)
  }

  for (int it = 0; it < 6; ++it){
    char* Ab = smem +         (it & 1)*16384;
    char* Bb = smem + 32768 + (it & 1)*16384;
    u32x4 pk0, pk1;
    pk0[0] = pkbf(ra0.x, ra0.y); pk0[1] = pkbf(ra0.z, ra0.w);
    pk0[2] = pkbf(ra1.x, ra1.y); pk0[3] = pkbf(ra1.z, ra1.w);
    pk1[0] = pkbf(ra2.x, ra2.y); pk1[1] = pkbf(ra2.z, ra2.w);
    pk1[2] = pkbf(ra3.x, ra3.y); pk1[3] = pkbf(ra3.z, ra3.w);
    *(u32x4*)(Ab + sr*256 + aslot)        = pk0;
    *(u32x4*)(Ab + sr*256 + 128 + aslot)  = pk1;
    u32x4 qb0, qb1;
    qb0[0] = pkbf(rb[0],  rb[1]);  qb0[1] = pkbf(rb[2],  rb[3]);
    qb0[2] = pkbf(rb[4],  rb[5]);  qb0[3] = pkbf(rb[6],  rb[7]);
    qb1[0] = pkbf(rb[8],  rb[9]);  qb1[1] = pkbf(rb[10], rb[11]);
    qb1[2] = pkbf(rb[12], rb[13]); qb1[3] = pkbf(rb[14], rb[15]);
    *(u32x4*)(Bb + ob*256 +       bslot0) = qb0;
    *(u32x4*)(Bb + ob*256 + 128 + bslot0) = qb1;
    __syncthreads();                       // single barrier per iter (dbuf)
    if (it < 5){
      const float* an = hA + (it+1)*128;
      ra0 = *(const float4*)(an);      ra1 = *(const float4*)(an + 4);
      ra2 = *(const float4*)(an + 64); ra3 = *(const float4*)(an + 68);
      const float* wn_ = wsrc + (size_t)(it+1)*128*FOUT;
      #pragma unroll
      for (int j = 0; j < 8; ++j){
        rb[j]     = wn_[(size_t)(cc*8 + j)*FOUT];
        rb[8 + j] = wn_[(size_t)(64 + cc*8 + j)*FOUT];
      }
    }
    #pragma unroll
    for (int s = 0; s < 4; ++s){
      const int slot = (((s*2 + h32) ^ (l32 & 7)) << 4);
      bf16x8 av = *(const bf16x8*)(Ab + (wm*32 + l32)*256 + kw*128 + slot);
      bf16x8 bv = *(const bf16x8*)(Bb + (wn*32 + l32)*256 + kw*128 + slot);
      acc = __builtin_amdgcn_mfma_f32_32x32x16_bf16(av, bv, acc, 0, 0, 0);
    }
  }

  // kw-merge via scratch@0 (A0 region; disjoint from iter-5's A1/B1 reads)
  if (kw == 1) *(f32x16*)(smem + (size_t)((wave & 3)*64 + lane)*64) = acc;
  __syncthreads();
  if (kw == 0){
    acc += *(const f32x16*)(smem + (size_t)((wave & 3)*64 + lane)*64);
    const float as = a_src[head*64 + wn*32 + l32];
    const float ad = a_dst[head*64 + wn*32 + l32];
    #pragma unroll
    for (int rb2 = 0; rb2 < 4; ++rb2){
      const int jb = wm*32 + rb2*8 + h32*4;
      u16x4 c4;
      #pragma unroll
      for (int q = 0; q < 4; ++q){
        const float v = acc[rb2*4 + q];
        c4[q] = f2bf(v);
        const float t = tanhf(v);
        float ps = t*as, pd = t*ad;
        ps += __shfl_xor(ps, 1);  ps += __shfl_xor(ps, 2);  ps += __shfl_xor(ps, 4);
        ps += __shfl_xor(ps, 8);  ps += __shfl_xor(ps, 16);
        pd += __shfl_xor(pd, 1);  pd += __shfl_xor(pd, 2);  pd += __shfl_xor(pd, 4);
        pd += __shfl_xor(pd, 8);  pd += __shfl_xor(pd, 16);
        if (l32 == 0){
          psumS[(jb + q)*2 + wn] = ps;
          psumD[(jb + q)*2 + wn] = pd;
        }
      }
      const int orow = wn*32 + l32;
      const int slot = ((jb >> 3) & 7) ^ (orow & 7);
      *(u16x4*)(Tt + orow*128 + slot*16 + (jb & 7)*2) = c4;
    }
  }
  __syncthreads();

  {
    const int o = tid & 63, c = tid >> 6;
    u16x8 val = *(const u16x8*)(Tt + o*128 + ((c ^ (o & 7)) << 4));
    *(u16x8*)((char*)hpz2 + ((size_t)(bh1*256 + (jbase >> 3) + c)*64 + o)*16) = val;
  }
  if (tid < 64){
    // log2-domain pre-scale; NO max subtraction needed downstream (bounded
    // inputs: |s|,|d| <= ~28.1 in log2 units -> exp2 range fp32-safe)
    srcv[(size_t)bh1*NSEQ + jbase + tid] = (psumS[tid*2] + psumS[tid*2 + 1]) * LOG2E;
    dstv[(size_t)bh1*NSEQ + jbase + tid] = (psumD[tid*2] + psumD[tid*2 + 1]) * LOG2E;
  }
}

// ---------------------------------------------------------------------------
// Kernel B v2: BARRIER-FREE main loop. hpz2[bh] is 256 KB and XCD-L2-resident
// (32 blocks of the same bh land on one XCD via the swizzle); the old LDS
// staging was an identity-layout L2->LDS copy costing 16 block-wide barriers
// per block. Now each wave loads its MFMA B-fragments directly from global
// (coalesced dwordx4, L2 hits), register-double-buffered; zero __syncthreads
// until the output epilogue. LDS shrinks to the 33 KB epilogue scratch.
// ---------------------------------------------------------------------------
__global__ __launch_bounds__(512, 4) void k_attn(
    const unsigned short* __restrict__ hpz2, const float* __restrict__ srcv,
    const float* __restrict__ dstv, const float* __restrict__ bias,
    float* __restrict__ out)
{
  __shared__ __align__(16) char smem[33792];   // ob@0 (32 KB), Lbuf@32768
  float* Lbuf = (float*)(smem + 32768);        // [8][32]

  const int tid = threadIdx.x;
  const int bid = blockIdx.x;
  const int bh  = (bid & 7) | (((bid >> 3) & 1) << 3);
  const int i0  = (bid >> 4) << 6;
  const int wave = tid >> 6, lane = tid & 63;
  const int wm = wave & 1, jw = wave >> 1;
  const int l32 = lane & 31, h32 = lane >> 5;

  const float s2 = srcv[(size_t)bh*NSEQ + i0 + wm*32 + l32];
  const float u_ = s2;                 // lrelu(s+d) = max(u_+d, 0.2d+v_)
  const float v_ = 0.2f*s2;

  // direct-global B fragments: unit(w,Jl,half,l32) = w*1024 + Jl*64 + half*32 + l32
  const u16x8* gp = (const u16x8*)((const char*)hpz2 + (size_t)bh*256*64*16);
  const u16x8* tp = gp + ((jw*4 + h32)*64 + l32);      // Jl0 row; Jl1 = +128
  const float* dS = dstv + (size_t)bh*NSEQ + (jw*4 + h32)*8;  // Jl0 j-chunk; Jl1 = +16

  f32x16 accO0 = {0,0,0,0,0,0,0,0,0,0,0,0,0,0,0,0};
  f32x16 accO1 = {0,0,0,0,0,0,0,0,0,0,0,0,0,0,0,0};
  float lpart = 0.f;

  u16x8 c0 = tp[0], c1 = tp[32], c2 = tp[128], c3 = tp[160];

  for (int w = 0; w < 16; ++w){
    u16x8 n0, n1, n2, n3;
    if (w < 15){
      const u16x8* np = tp + 1024;
      n0 = np[0]; n1 = np[32]; n2 = np[128]; n3 = np[160];
    }
    float4 d0 = *(const float4*)(dS);
    float4 d1 = *(const float4*)(dS + 4);
    float4 d2 = *(const float4*)(dS + 16);
    float4 d3 = *(const float4*)(dS + 20);
    // stl0 (rows jw*4 + h32)
    {
      float e0 = fexp2(fmaxf(u_ + d0.x, fmaf(0.2f, d0.x, v_)));
      float e1 = fexp2(fmaxf(u_ + d0.y, fmaf(0.2f, d0.y, v_)));
      float e2 = fexp2(fmaxf(u_ + d0.z, fmaf(0.2f, d0.z, v_)));
      float e3 = fexp2(fmaxf(u_ + d0.w, fmaf(0.2f, d0.w, v_)));
      float e4 = fexp2(fmaxf(u_ + d1.x, fmaf(0.2f, d1.x, v_)));
      float e5 = fexp2(fmaxf(u_ + d1.y, fmaf(0.2f, d1.y, v_)));
      float e6 = fexp2(fmaxf(u_ + d1.z, fmaf(0.2f, d1.z, v_)));
      float e7 = fexp2(fmaxf(u_ + d1.w, fmaf(0.2f, d1.w, v_)));
      lpart += ((e0+e1)+(e2+e3)) + ((e4+e5)+(e6+e7));
      u32x4 pk;
      pk[0] = pkbf(e0, e1); pk[1] = pkbf(e2, e3);
      pk[2] = pkbf(e4, e5); pk[3] = pkbf(e6, e7);
      const bf16x8 pA = __builtin_bit_cast(bf16x8, pk);
      accO0 = __builtin_amdgcn_mfma_f32_32x32x16_bf16(pA, c0, accO0, 0, 0, 0);
      accO1 = __builtin_amdgcn_mfma_f32_32x32x16_bf16(pA, c1, accO1, 0, 0, 0);
    }
    // stl1 (rows jw*4 + 2 + h32)
    {
      float e0 = fexp2(fmaxf(u_ + d2.x, fmaf(0.2f, d2.x, v_)));
      float e1 = fexp2(fmaxf(u_ + d2.y, fmaf(0.2f, d2.y, v_)));
      float e2 = fexp2(fmaxf(u_ + d2.z, fmaf(0.2f, d2.z, v_)));
      float e3 = fexp2(fmaxf(u_ + d2.w, fmaf(0.2f, d2.w, v_)));
      float e4 = fexp2(fmaxf(u_ + d3.x, fmaf(0.2f, d3.x, v_)));
      float e5 = fexp2(fmaxf(u_ + d3.y, fmaf(0.2f, d3.y, v_)));
      float e6 = fexp2(fmaxf(u_ + d3.z, fmaf(0.2f, d3.z, v_)));
      float e7 = fexp2(fmaxf(u_ + d3.w, fmaf(0.2f, d3.w, v_)));
      lpart += ((e0+e1)+(e2+e3)) + ((e4+e5)+(e6+e7));
      u32x4 pk;
      pk[0] = pkbf(e0, e1); pk[1] = pkbf(e2, e3);
      pk[2] = pkbf(e4, e5); pk[3] = pkbf(e6, e7);
      const bf16x8 pA = __builtin_bit_cast(bf16x8, pk);
      accO0 = __builtin_amdgcn_mfma_f32_32x32x16_bf16(pA, c2, accO0, 0, 0, 0);
      accO1 = __builtin_amdgcn_mfma_f32_32x32x16_bf16(pA, c3, accO1, 0, 0, 0);
    }
    tp += 1024; dS += 128;
    c0 = n0; c1 = n1; c2 = n2; c3 = n3;
  }

  lpart += __shfl_xor(lpart, 32);
  if (lane < 32) Lbuf[(wm*4 + jw)*32 + l32] = lpart;

  const float4 bia = *(const float4*)(bias + (tid & 15)*4);
  #pragma unroll
  for (int ph = 0; ph < 2; ++ph){
    __syncthreads();
    if (wm == ph){
      float* ob = (float*)smem;            // [jw][m 32][o 64] fp32 = 32 KB
      #pragma unroll
      for (int reg = 0; reg < 16; ++reg){
        const int m = (reg & 3) + 8*(reg >> 2) + 4*h32;
        ob[(jw*32 + m)*64 +      l32] = accO0[reg];
        ob[(jw*32 + m)*64 + 32 + l32] = accO1[reg];
      }
    }
    __syncthreads();
    {
      const int i = tid >> 4, o4 = (tid & 15)*4;
      const float* ob = (const float*)smem;
      float4 v0 = *(const float4*)(ob + (0*32 + i)*64 + o4);
      float4 v1 = *(const float4*)(ob + (1*32 + i)*64 + o4);
      float4 v2 = *(const float4*)(ob + (2*32 + i)*64 + o4);
      float4 v3 = *(const float4*)(ob + (3*32 + i)*64 + o4);
      const float l = Lbuf[(ph*4+0)*32 + i] + Lbuf[(ph*4+1)*32 + i]
                    + Lbuf[(ph*4+2)*32 + i] + Lbuf[(ph*4+3)*32 + i];
      const float r = 1.f / l;
      float4 res;
      res.x = (v0.x + v1.x + v2.x + v3.x)*r + bia.x;
      res.y = (v0.y + v1.y + v2.y + v3.y)*r + bia.y;
      res.z = (v0.z + v1.z + v2.z + v3.z)*r + bia.z;
      res.w = (v0.w + v1.w + v2.w + v3.w)*r + bia.w;
      *(float4*)(out + ((size_t)bh*NSEQ + i0 + ph*32 + i)*64 + o4) = res;
    }
  }
}

// ---------------------------------------------------------------------------
extern "C" void kernel_launch(void* const* d_in, const int* in_sizes, int n_in,
                              void* d_out, int out_size, void* d_ws, size_t ws_size,
                              hipStream_t stream)
{
  const float* h     = (const float*)d_in[0];
  const float* w     = (const float*)d_in[1];
  const float* a_src = (const float*)d_in[2];
  const float* a_dst = (const float*)d_in[3];
  const float* bias  = (const float*)d_in[4];
  float* out = (float*)d_out;

  char* ws = (char*)d_ws;
  unsigned short* hpz2 = (unsigned short*)ws;                 // 4 MB bf16 chunk-linear
  float* srcv = (float*)(ws + (4u<<20));                      // 128 KB (log2-scaled)
  float* dstv = (float*)(ws + (4u<<20) + (128u<<10));         // 128 KB (log2-scaled)

  k_hprime<<<512, 512, 0, stream>>>(h, w, a_src, a_dst, hpz2, srcv, dstv);
  k_attn<<<512, 512, 0, stream>>>(hpz2, srcv, dstv, bias, out);
}